// Round 1
// baseline (29.930 us; speedup 1.0000x reference)
//
#include <hip/hip_runtime.h>

// EdgeSelectionRL: out[b,i,j] = sigmoid( sum_h relu(A[b,i,h] + Cc[b,j,h]) * w2[h] + b2 )
// where A = xa·Wa^T + b1 (b1 folded in), Cc = xa·Wb^T.
// B=8, C=256, F=128, H=256. Compute-bound on VALU (~403M lane-ops -> ~5.1us floor).

constexpr int B  = 8;
constexpr int C  = 256;
constexpr int F  = 128;
constexpr int H  = 256;
constexpr int F2 = 2 * F;   // 256
constexpr int H4 = H / 4;   // 64

// ---------------- Kernel 1: fused projections ----------------
// Block computes a 16i x 16h tile of BOTH A and Cc for one batch.
// A stored row-major [b][i][h]; Cc stored h-packed: float component
// CP[((b*H4 + h/4)*C + j)*4 + (h&3)] so k2 reads float4 over 4 consecutive h.
constexpr int T1 = 16;
constexpr int XPITCH = F + 4;    // 132 words -> bank-conflict-free tile reads
constexpr int WPITCH = F2 + 4;   // 260 words

__global__ __launch_bounds__(256) void k1_proj(
    const float* __restrict__ xa, const float* __restrict__ W1,
    const float* __restrict__ b1, float* __restrict__ A, float* __restrict__ CP)
{
    __shared__ float xs[T1 * XPITCH];
    __shared__ float ws[T1 * WPITCH];
    const int t   = threadIdx.x;
    const int blk = blockIdx.x;
    const int ht  = blk & 15;
    const int it  = (blk >> 4) & 15;
    const int b   = blk >> 8;
    const int i0  = it * T1, h0 = ht * T1;

    // stage xa tile: 16 rows x 128 floats (512 float4)
    {
        const float4* src = (const float4*)(xa + (size_t)(b * C + i0) * F);
        for (int idx = t; idx < T1 * (F / 4); idx += 256) {
            int r = idx >> 5, c = idx & 31;
            float4 v = src[r * (F / 4) + c];
            *(float4*)&xs[r * XPITCH + c * 4] = v;
        }
        // stage W1 tile: 16 h-rows x 256 floats (covers Wa and Wb halves)
        const float4* wsrc = (const float4*)(W1 + (size_t)h0 * F2);
        for (int idx = t; idx < T1 * (F2 / 4); idx += 256) {
            int r = idx >> 6, c = idx & 63;
            float4 v = wsrc[r * (F2 / 4) + c];
            *(float4*)&ws[r * WPITCH + c * 4] = v;
        }
    }
    __syncthreads();

    const int h = t & 15, i = t >> 4;  // h fastest -> coalesced A store
    float accA = 0.f, accC = 0.f;
    #pragma unroll
    for (int c = 0; c < F / 4; ++c) {
        float4 xv = *(const float4*)&xs[i * XPITCH + c * 4];
        float4 wa = *(const float4*)&ws[h * WPITCH + c * 4];
        float4 wb = *(const float4*)&ws[h * WPITCH + F + c * 4];
        accA = fmaf(xv.x, wa.x, accA); accA = fmaf(xv.y, wa.y, accA);
        accA = fmaf(xv.z, wa.z, accA); accA = fmaf(xv.w, wa.w, accA);
        accC = fmaf(xv.x, wb.x, accC); accC = fmaf(xv.y, wb.y, accC);
        accC = fmaf(xv.z, wb.z, accC); accC = fmaf(xv.w, wb.w, accC);
    }
    const int hg = h0 + h;
    accA += b1[hg];
    A[(size_t)(b * C + i0 + i) * H + hg] = accA;
    CP[((size_t)(b * H4 + (hg >> 2)) * C + (i0 + i)) * 4 + (hg & 3)] = accC;
}

// ---------------- Kernel 2: pairwise relu-reduce + sigmoid ----------------
// Block = (b, 8-row i-tile). 512 threads: j = t&255, h-half = t>>8.
// CP[b] slab (256 KB) read exactly once per block; A-tile + w2 broadcast from LDS.
constexpr int TI = 8;

__global__ __launch_bounds__(512) void k2_pair(
    const float* __restrict__ A, const float4* __restrict__ CP4,
    const float* __restrict__ w2, const float* __restrict__ b2p,
    float* __restrict__ out)
{
    __shared__ float4 As[TI * H4];   // A rows as float4 over h
    __shared__ float4 w2s[H4];
    __shared__ float  red[TI * C];
    const int t   = threadIdx.x;
    const int blk = blockIdx.x;
    const int it  = blk & 31;
    const int b   = blk >> 5;
    const int i0  = it * TI;

    {
        const float4* src = (const float4*)(A + (size_t)(b * C + i0) * H);
        As[t] = src[t];                       // 512 float4 = 8 rows x 64
        if (t < H4) w2s[t] = ((const float4*)w2)[t];
    }
    __syncthreads();

    const int j  = t & 255;
    const int hh = t >> 8;                    // uniform per wave
    float acc[TI];
    #pragma unroll
    for (int ii = 0; ii < TI; ++ii) acc[ii] = 0.f;

    const float4* cp = CP4 + (size_t)(b * H4) * C + j;
    const int h4lo = hh * (H4 / 2);
    #pragma unroll 2
    for (int h4 = h4lo; h4 < h4lo + H4 / 2; ++h4) {
        float4 cc = cp[(size_t)h4 * C];       // coalesced 16B/lane
        float4 w  = w2s[h4];                  // broadcast
        #pragma unroll
        for (int ii = 0; ii < TI; ++ii) {
            float4 av = As[ii * H4 + h4];     // broadcast
            float s = acc[ii];
            s = fmaf(fmaxf(av.x + cc.x, 0.f), w.x, s);
            s = fmaf(fmaxf(av.y + cc.y, 0.f), w.y, s);
            s = fmaf(fmaxf(av.z + cc.z, 0.f), w.z, s);
            s = fmaf(fmaxf(av.w + cc.w, 0.f), w.w, s);
            acc[ii] = s;
        }
    }

    if (hh == 1) {
        #pragma unroll
        for (int ii = 0; ii < TI; ++ii) red[ii * C + j] = acc[ii];
    }
    __syncthreads();
    if (hh == 0) {
        const float bb = b2p[0];
        #pragma unroll
        for (int ii = 0; ii < TI; ++ii) {
            float x = acc[ii] + red[ii * C + j] + bb;
            out[(size_t)(b * C + i0 + ii) * C + j] = 1.f / (1.f + __expf(-x));
        }
    }
}

extern "C" void kernel_launch(void* const* d_in, const int* in_sizes, int n_in,
                              void* d_out, int out_size, void* d_ws, size_t ws_size,
                              hipStream_t stream) {
    const float* xa = (const float*)d_in[0];
    const float* W1 = (const float*)d_in[1];
    const float* b1 = (const float*)d_in[2];
    const float* w2 = (const float*)d_in[3];
    const float* b2 = (const float*)d_in[4];
    float* out = (float*)d_out;

    float* A  = (float*)d_ws;                 // B*C*H floats = 2 MB
    float* CP = A + (size_t)B * C * H;        // B*H*C floats = 2 MB (h-packed)

    k1_proj<<<B * 16 * 16, 256, 0, stream>>>(xa, W1, b1, A, CP);
    k2_pair<<<B * (C / TI), 512, 0, stream>>>(A, (const float4*)CP, w2, b2, out);
}

// Round 2
// 26.480 us; speedup vs baseline: 1.1303x; 1.1303x over previous
//
#include <hip/hip_runtime.h>

// EdgeSelectionRL: out[b,i,j] = sigmoid( sum_h relu(A[b,i,h] + Cc[b,j,h]) * w2[h] + b2 )
// A = xa·Wa^T + b1, Cc = xa·Wb^T.  B=8, C=256, F=128, H=256.
// R2: fp16 storage + v_dot2_f32_f16 (VALU floor 5.1->2.56us), A via wave-uniform
// scalar loads (kills the LDS-broadcast bottleneck), 4 waves/SIMD occupancy.

typedef _Float16 h2 __attribute__((ext_vector_type(2)));
typedef _Float16 h8 __attribute__((ext_vector_type(8)));

constexpr int B  = 8;
constexpr int C  = 256;
constexpr int F  = 128;
constexpr int H  = 256;
constexpr int F2 = 2 * F;     // 256
constexpr int HOCT = H / 8;   // 32 octets of h

#if __has_builtin(__builtin_amdgcn_fdot2)
__device__ __forceinline__ float fdot2(h2 a, h2 b, float c) {
    return __builtin_amdgcn_fdot2(a, b, c, false);
}
#else
__device__ __forceinline__ float fdot2(h2 a, h2 b, float c) {
    return c + (float)a.x * (float)b.x + (float)a.y * (float)b.y;
}
#endif

// ---------------- Kernel 1: fused projections (fp32 math, fp16 outputs) ----
constexpr int T1 = 16;
constexpr int XP = F + 4;     // 132
constexpr int WP = F2 + 4;    // 260

__global__ __launch_bounds__(256) void k1_proj(
    const float* __restrict__ xa, const float* __restrict__ W1,
    const float* __restrict__ b1, const float* __restrict__ w2,
    _Float16* __restrict__ Ah, _Float16* __restrict__ CP8,
    _Float16* __restrict__ w2h)
{
    __shared__ float xs[T1 * XP];
    __shared__ float ws[T1 * WP];
    const int t   = threadIdx.x;
    const int blk = blockIdx.x;
    const int ht  = blk & 15;
    const int it  = (blk >> 4) & 15;
    const int b   = blk >> 8;
    const int i0  = it * T1, h0 = ht * T1;

    {
        const float4* src = (const float4*)(xa + (size_t)(b * C + i0) * F);
        for (int idx = t; idx < T1 * (F / 4); idx += 256) {
            int r = idx >> 5, c = idx & 31;
            *(float4*)&xs[r * XP + c * 4] = src[r * (F / 4) + c];
        }
        const float4* wsrc = (const float4*)(W1 + (size_t)h0 * F2);
        for (int idx = t; idx < T1 * (F2 / 4); idx += 256) {
            int r = idx >> 6, c = idx & 63;
            *(float4*)&ws[r * WP + c * 4] = wsrc[r * (F2 / 4) + c];
        }
    }
    if (blk == 0 && t < 128) {   // w2 -> fp16 once
        float2 wv = ((const float2*)w2)[t];
        h2 hv = {(_Float16)wv.x, (_Float16)wv.y};
        ((h2*)w2h)[t] = hv;
    }
    __syncthreads();

    const int h = t & 15, i = t >> 4;
    float accA = 0.f, accC = 0.f;
    #pragma unroll
    for (int c = 0; c < F / 4; ++c) {
        float4 xv = *(const float4*)&xs[i * XP + c * 4];
        float4 wa = *(const float4*)&ws[h * WP + c * 4];
        float4 wb = *(const float4*)&ws[h * WP + F + c * 4];
        accA = fmaf(xv.x, wa.x, accA); accA = fmaf(xv.y, wa.y, accA);
        accA = fmaf(xv.z, wa.z, accA); accA = fmaf(xv.w, wa.w, accA);
        accC = fmaf(xv.x, wb.x, accC); accC = fmaf(xv.y, wb.y, accC);
        accC = fmaf(xv.z, wb.z, accC); accC = fmaf(xv.w, wb.w, accC);
    }
    const int hg = h0 + h;
    accA += b1[hg];
    Ah[(size_t)(b * C + i0 + i) * H + hg] = (_Float16)accA;
    // h-octet-packed Cc: CP8[((b*HOCT + h/8)*C + j)*8 + (h&7)]
    CP8[(((size_t)(b * HOCT + (hg >> 3)) * C + (i0 + i)) << 3) + (hg & 7)] = (_Float16)accC;
}

// ---------------- Kernel 2: pairwise relu-dot + sigmoid --------------------
// Block = (b, 8 i-rows): 1024 threads = 256 j x 4 h-splits (16 waves, 4/SIMD).
// A octets are wave-uniform -> scalar loads; Cc octets 16B/lane coalesced.
constexpr int TI = 8;
constexpr int HS = 4;

__global__ __launch_bounds__(1024) void k2_pair(
    const _Float16* __restrict__ Ah, const _Float16* __restrict__ CP8,
    const _Float16* __restrict__ w2h, const float* __restrict__ b2p,
    float* __restrict__ out)
{
    __shared__ float red[(HS - 1) * TI * C];   // 24 KB
    const int t   = threadIdx.x;
    const int j   = t & 255;
    const int hs  = t >> 8;                    // wave-uniform
    const int blk = blockIdx.x;
    const int it  = blk & 31;
    const int b   = blk >> 5;
    const int i0  = it * TI;

    float acc[TI];
    #pragma unroll
    for (int ii = 0; ii < TI; ++ii) acc[ii] = 0.f;

    const int g0 = hs * (HOCT / HS);           // 8 octets per split
    const _Float16* Ab = Ah + (size_t)(b * C + i0) * H;

    union U { h8 v; h2 p[4]; };
    #pragma unroll 2
    for (int g = 0; g < HOCT / HS; ++g) {
        const int hb = g0 + g;
        h8 cc = *(const h8*)(CP8 + (((size_t)(b * HOCT + hb) * C + j) << 3));
        U uw; uw.v = *(const h8*)(w2h + hb * 8);          // uniform
        #pragma unroll
        for (int ii = 0; ii < TI; ++ii) {
            h8 av = *(const h8*)(Ab + ii * H + hb * 8);   // uniform -> s_load
            h8 s = av + cc;                                // v_pk_add_f16
            h8 z = {0, 0, 0, 0, 0, 0, 0, 0};
            s = __builtin_elementwise_max(s, z);           // v_pk_max_f16
            U us; us.v = s;
            float a0 = acc[ii];
            a0 = fdot2(us.p[0], uw.p[0], a0);              // v_dot2_f32_f16
            a0 = fdot2(us.p[1], uw.p[1], a0);
            a0 = fdot2(us.p[2], uw.p[2], a0);
            a0 = fdot2(us.p[3], uw.p[3], a0);
            acc[ii] = a0;
        }
    }

    if (hs > 0) {
        #pragma unroll
        for (int ii = 0; ii < TI; ++ii)
            red[((hs - 1) * TI + ii) * C + j] = acc[ii];
    }
    __syncthreads();
    if (hs == 0) {
        const float bb = b2p[0];
        #pragma unroll
        for (int ii = 0; ii < TI; ++ii) {
            float x = acc[ii]
                    + red[(0 * TI + ii) * C + j]
                    + red[(1 * TI + ii) * C + j]
                    + red[(2 * TI + ii) * C + j] + bb;
            out[(size_t)(b * C + i0 + ii) * C + j] = 1.f / (1.f + __expf(-x));
        }
    }
}

extern "C" void kernel_launch(void* const* d_in, const int* in_sizes, int n_in,
                              void* d_out, int out_size, void* d_ws, size_t ws_size,
                              hipStream_t stream) {
    const float* xa = (const float*)d_in[0];
    const float* W1 = (const float*)d_in[1];
    const float* b1 = (const float*)d_in[2];
    const float* w2 = (const float*)d_in[3];
    const float* b2 = (const float*)d_in[4];
    float* out = (float*)d_out;

    _Float16* Ah  = (_Float16*)d_ws;                  // 1 MB
    _Float16* CP8 = Ah + (size_t)B * C * H;           // 1 MB
    _Float16* w2h = CP8 + (size_t)B * H * C;          // 512 B

    k1_proj<<<B * 16 * 16, 256, 0, stream>>>(xa, W1, b1, w2, Ah, CP8, w2h);
    k2_pair<<<B * (C / TI), 1024, 0, stream>>>(Ah, CP8, w2h, b2, out);
}